// Round 5
// baseline (466.287 us; speedup 1.0000x reference)
//
#include <hip/hip_runtime.h>

// LinOSS: damped-oscillator linear SSM scan. B=8, T=2048, H=16, D=64.
//   sigma = sigmoid(osc_damp); a = DT*exp(osc_w)   (per h,d,e element)
//   z' = (1-sigma)*z - a*y + DT*beta*k[d]*v[e]
//   y' = y + DT*z'
//   out[b,t,h,e] = (1/8) * sum_d q[b,t,h,d] * y[d,e]
//
// Chunk-parallel over T (constant-coefficient recurrence):
//   tail pass: chunks 0..NC-2 from zero state, store final (y,z) to ws.
//   main pass: chunk c start = sum_i (A^L)^(c-1-i) c_i via 2x2 squarings.
//
// Occupancy history: launch_bounds arg2 empirically CAPS waves/EU on this
// stack (R1: arg2=1 -> 12%; R2/R4: arg2=4 -> ~40%; R3: arg2=8 -> 94% but
// regalloc spilled to 32 VGPR). Fix: amdgpu_waves_per_eu(4,8) = regalloc
// budget of min=4 (128 regs, natural 56 fits) + scheduler max of 8.

constexpr float DTc = 0.01f;
constexpr int Tn = 2048, Hn = 16, Dn = 64;
constexpr int TS = Hn * Dn; // 1024 floats per t-step in q/k/v/out

struct Slot {
    float4 qa, qb, ka, kb;
    float vv, bb;
};

template<bool WQ>
__device__ __forceinline__ void loadSlot(Slot& s,
                                         const float* __restrict__ qp,
                                         const float* __restrict__ kp,
                                         const float* __restrict__ vp,
                                         const float* __restrict__ bp,
                                         int t) {
    size_t o = (size_t)t * TS;
    const float4* k4 = (const float4*)(kp + o);
    s.ka = k4[0];
    s.kb = k4[1];
    if (WQ) {
        const float4* q4 = (const float4*)(qp + o);
        s.qa = q4[0];
        s.qb = q4[1];
    }
    s.vv = vp[o];
    s.bb = bp[(size_t)t * Hn];
}

template<bool WQ>
__device__ __forceinline__ void stepT(const Slot& s,
                                      float* __restrict__ y, float* __restrict__ z,
                                      const float* __restrict__ aDT,
                                      const float* __restrict__ omc,
                                      float* __restrict__ op,
                                      int t, bool wlane) {
    float bv = (DTc * s.bb) * s.vv; // DT*beta*v[e]
    float kk[8] = {s.ka.x, s.ka.y, s.ka.z, s.ka.w, s.kb.x, s.kb.y, s.kb.z, s.kb.w};
    float p = 0.0f;
#pragma unroll
    for (int j = 0; j < 8; ++j) {
        float kv = bv * kk[j];
        z[j] = fmaf(omc[j], z[j], fmaf(-aDT[j], y[j], kv));
        y[j] = fmaf(DTc, z[j], y[j]);
    }
    if (WQ) {
        float qq[8] = {s.qa.x, s.qa.y, s.qa.z, s.qa.w, s.qb.x, s.qb.y, s.qb.z, s.qb.w};
#pragma unroll
        for (int j = 0; j < 8; ++j) p = fmaf(qq[j], y[j], p);
        p += __shfl_xor(p, 1);
        p += __shfl_xor(p, 2);
        p += __shfl_xor(p, 4);
        if (wlane) op[(size_t)t * TS] = p * 0.125f; // scale = D^-0.5
    }
}

// TAIL: chunks 0..NC-2, no q/out, store final state to ws.
// !TAIL: chunks 0..NC-1, reconstruct start state from ws, write out.
template<int NC, bool TAIL>
__global__ __launch_bounds__(256)
__attribute__((amdgpu_waves_per_eu(4, 8)))
void linoss_k(const float* __restrict__ Q, const float* __restrict__ K,
              const float* __restrict__ V, const float* __restrict__ Bt,
              const float* __restrict__ OW, const float* __restrict__ OD,
              float* __restrict__ Out, float* __restrict__ WS) {
    constexpr int L = Tn / NC;
    int blk = blockIdx.x;
    int c = blk >> 8;       // chunk index
    int sl = blk & 255;
    // XCD-aware decode: both e-halves of the same (b,h) on one XCD.
    int xcd = sl & 7, slot = sl >> 3;
    int ec = slot & 1;
    int bh = ((slot >> 1) << 3) | xcd;
    int b = bh >> 4, h = bh & 15;

    int tid = threadIdx.x;
    int dgrp = tid & 7;
    int el = tid >> 3;
    int e = ec * 32 + el;
    int d0 = dgrp * 8;

    float aDT[8], omc[8];
#pragma unroll
    for (int j = 0; j < 8; ++j) {
        int idx = (h * Dn + d0 + j) * Dn + e;
        aDT[j] = DTc * expf(OW[idx]);
        float sg = 1.0f / (1.0f + expf(-OD[idx]));
        omc[j] = 1.0f - sg;
    }

    float y[8], z[8];
#pragma unroll
    for (int j = 0; j < 8; ++j) { y[j] = 0.0f; z[j] = 0.0f; }

    // per-(c,bh,ec) ws tile: 256 threads x 8 elems x {y,z}
    auto wsBase = [&](int ci) {
        return WS + (((size_t)ci * 128 + bh) * 2 + ec) * 4096 + (size_t)tid * 16;
    };

    if (!TAIL && c > 0) {
        // A = [[1-DT*a, DT*w],[-a, w]] on (y,z); compute A^L by squaring.
        float m00[8], m01[8], m10[8], m11[8];
#pragma unroll
        for (int j = 0; j < 8; ++j) {
            m00[j] = 1.0f - DTc * aDT[j];
            m01[j] = DTc * omc[j];
            m10[j] = -aDT[j];
            m11[j] = omc[j];
        }
        for (int pw = 1; pw < L; pw <<= 1) {
#pragma unroll
            for (int j = 0; j < 8; ++j) {
                float n00 = fmaf(m00[j], m00[j], m01[j] * m10[j]);
                float n01 = fmaf(m00[j], m01[j], m01[j] * m11[j]);
                float n10 = fmaf(m10[j], m00[j], m11[j] * m10[j]);
                float n11 = fmaf(m10[j], m01[j], m11[j] * m11[j]);
                m00[j] = n00; m01[j] = n01; m10[j] = n10; m11[j] = n11;
            }
        }
        // s = 0; for i in [0,c): s = A^L * s + c_i
        for (int i = 0; i < c; ++i) {
            const float4* cw = (const float4*)wsBase(i);
            float4 w0 = cw[0], w1 = cw[1], w2 = cw[2], w3 = cw[3];
            float cy[8] = {w0.x, w0.z, w1.x, w1.z, w2.x, w2.z, w3.x, w3.z};
            float cz[8] = {w0.y, w0.w, w1.y, w1.w, w2.y, w2.w, w3.y, w3.w};
#pragma unroll
            for (int j = 0; j < 8; ++j) {
                float ny = fmaf(m00[j], y[j], fmaf(m01[j], z[j], cy[j]));
                float nz = fmaf(m10[j], y[j], fmaf(m11[j], z[j], cz[j]));
                y[j] = ny; z[j] = nz;
            }
        }
    }

    size_t base = ((size_t)b * Tn * Hn + h) * Dn;
    const float* qp = Q + base + d0;
    const float* kp = K + base + d0;
    const float* vp = V + base + e;
    const float* bp = Bt + (size_t)b * Tn * Hn + h;
    float* op = Out + base + e;
    bool wlane = (dgrp == 0);

    constexpr bool WQ = !TAIL;
    int t0 = c * L, t1 = t0 + L;

    Slot s0, s1, s2, s3;
    loadSlot<WQ>(s0, qp, kp, vp, bp, t0);
    loadSlot<WQ>(s1, qp, kp, vp, bp, t0 + 1);

    for (int t = t0; t < t1; t += 4) {
        loadSlot<WQ>(s2, qp, kp, vp, bp, (t + 2 < t1) ? t + 2 : t1 - 1);
        stepT<WQ>(s0, y, z, aDT, omc, op, t, wlane);
        loadSlot<WQ>(s3, qp, kp, vp, bp, (t + 3 < t1) ? t + 3 : t1 - 1);
        stepT<WQ>(s1, y, z, aDT, omc, op, t + 1, wlane);
        loadSlot<WQ>(s0, qp, kp, vp, bp, (t + 4 < t1) ? t + 4 : t1 - 1);
        stepT<WQ>(s2, y, z, aDT, omc, op, t + 2, wlane);
        loadSlot<WQ>(s1, qp, kp, vp, bp, (t + 5 < t1) ? t + 5 : t1 - 1);
        stepT<WQ>(s3, y, z, aDT, omc, op, t + 3, wlane);
    }

    if (TAIL) {
        float4* cw = (float4*)wsBase(c);
#pragma unroll
        for (int j = 0; j < 4; ++j) {
            float4 w;
            w.x = y[2 * j];     w.y = z[2 * j];
            w.z = y[2 * j + 1]; w.w = z[2 * j + 1];
            cw[j] = w;
        }
    }
}

extern "C" void kernel_launch(void* const* d_in, const int* in_sizes, int n_in,
                              void* d_out, int out_size, void* d_ws, size_t ws_size,
                              hipStream_t stream) {
    const float* q  = (const float*)d_in[0];
    const float* k  = (const float*)d_in[1];
    const float* v  = (const float*)d_in[2];
    const float* bt = (const float*)d_in[3];
    const float* ow = (const float*)d_in[4];
    const float* od = (const float*)d_in[5];
    float* out = (float*)d_out;
    float* ws = (float*)d_ws;

    const size_t chunkBytes = (size_t)128 * 2 * 4096 * sizeof(float); // 4 MiB

    if (ws_size >= 7 * chunkBytes) {
        hipLaunchKernelGGL((linoss_k<8, true>),  dim3(1792), dim3(256), 0, stream,
                           q, k, v, bt, ow, od, out, ws);
        hipLaunchKernelGGL((linoss_k<8, false>), dim3(2048), dim3(256), 0, stream,
                           q, k, v, bt, ow, od, out, ws);
    } else if (ws_size >= 3 * chunkBytes) {
        hipLaunchKernelGGL((linoss_k<4, true>),  dim3(768),  dim3(256), 0, stream,
                           q, k, v, bt, ow, od, out, ws);
        hipLaunchKernelGGL((linoss_k<4, false>), dim3(1024), dim3(256), 0, stream,
                           q, k, v, bt, ow, od, out, ws);
    } else if (ws_size >= chunkBytes) {
        hipLaunchKernelGGL((linoss_k<2, true>),  dim3(256),  dim3(256), 0, stream,
                           q, k, v, bt, ow, od, out, ws);
        hipLaunchKernelGGL((linoss_k<2, false>), dim3(512),  dim3(256), 0, stream,
                           q, k, v, bt, ow, od, out, ws);
    } else {
        hipLaunchKernelGGL((linoss_k<1, false>), dim3(256),  dim3(256), 0, stream,
                           q, k, v, bt, ow, od, out, ws);
    }
}

// Round 6
// 305.015 us; speedup vs baseline: 1.5287x; 1.5287x over previous
//
#include <hip/hip_runtime.h>

// LinOSS: damped-oscillator linear SSM scan. B=8, T=2048, H=16, D=64.
//   sigma = sigmoid(osc_damp); a = DT*exp(osc_w)   (per h,d,e element)
//   z' = (1-sigma)*z - a*y + DT*beta*k[d]*v[e]
//   y' = y + DT*z'
//   out[b,t,h,e] = (1/8) * sum_d q[b,t,h,d] * y[d,e]
//
// Chunk-parallel over T (constant-coefficient recurrence):
//   tail pass: chunks 0..NC-2 from zero state, store final (y,z) to ws.
//   main pass: chunk c start = sum_i (A^L)^(c-1-i) c_i via 2x2 squarings.
//
// R5 lesson: occupancy is pinned to launch_bounds' min-waves (4/SIMD); raising
// it spills (R3). So hide HBM latency at FIXED occupancy: stage q/k/v/beta
// tiles (TILE=16 steps) into LDS via global_load_lds (no VGPR round-trip),
// double-buffered; issue next tile's DMA before computing current tile
// (~1300 cyc compute >> ~900 cyc HBM latency). One __syncthreads per tile.

constexpr float DTc = 0.01f;
constexpr int Tn = 2048, Hn = 16, Dn = 64;
constexpr int TS = Hn * Dn; // 1024 floats per t-step in q/k/v/out
constexpr int TILE = 16;

typedef const __attribute__((address_space(1))) void* as1_cvp;
typedef __attribute__((address_space(3))) void* as3_vp;

__device__ __forceinline__ void gload_lds4(const float* g, float* lds) {
    // 4B per lane; LDS dst = wave-uniform base + lane*4 (contiguous 256B/wave)
    __builtin_amdgcn_global_load_lds((as1_cvp)g, (as3_vp)lds, 4, 0, 0);
}

// TAIL: chunks 0..NC-2, no q/out, store final state to ws.
// !TAIL: chunks 0..NC-1, reconstruct start state from ws, write out.
template<int NC, bool TAIL>
__global__ __launch_bounds__(256, 4)
void linoss_k(const float* __restrict__ Q, const float* __restrict__ K,
              const float* __restrict__ V, const float* __restrict__ Bt,
              const float* __restrict__ OW, const float* __restrict__ OD,
              float* __restrict__ Out, float* __restrict__ WS) {
    constexpr int L = Tn / NC;
    constexpr bool WQ = !TAIL;

    __shared__ float sK[2][TILE][64];
    __shared__ float sQ[2][TILE][64];
    __shared__ float sV[2][TILE][32];
    __shared__ float sB[2][TILE];

    int blk = blockIdx.x;
    int c = blk >> 8;       // chunk index
    int sl = blk & 255;
    // XCD-aware decode: both e-halves of the same (b,h) on one XCD.
    int xcd = sl & 7, slot = sl >> 3;
    int ec = slot & 1;
    int bh = ((slot >> 1) << 3) | xcd;
    int b = bh >> 4, h = bh & 15;

    int tid = threadIdx.x;
    int dgrp = tid & 7;
    int el = tid >> 3;
    int e = ec * 32 + el;
    int d0 = dgrp * 8;
    int wv = tid >> 6;      // wave id 0..3
    int ln = tid & 63;      // lane

    float aDT[8], omc[8];
#pragma unroll
    for (int j = 0; j < 8; ++j) {
        int idx = (h * Dn + d0 + j) * Dn + e;
        aDT[j] = DTc * expf(OW[idx]);
        float sg = 1.0f / (1.0f + expf(-OD[idx]));
        omc[j] = 1.0f - sg;
    }

    float y[8], z[8];
#pragma unroll
    for (int j = 0; j < 8; ++j) { y[j] = 0.0f; z[j] = 0.0f; }

    // per-(c,bh,ec) ws tile: 256 threads x 8 elems x {y,z}
    auto wsBase = [&](int ci) {
        return WS + (((size_t)ci * 128 + bh) * 2 + ec) * 4096 + (size_t)tid * 16;
    };

    if (!TAIL && c > 0) {
        // A = [[1-DT*a, DT*w],[-a, w]] on (y,z); compute A^L by squaring.
        float m00[8], m01[8], m10[8], m11[8];
#pragma unroll
        for (int j = 0; j < 8; ++j) {
            m00[j] = 1.0f - DTc * aDT[j];
            m01[j] = DTc * omc[j];
            m10[j] = -aDT[j];
            m11[j] = omc[j];
        }
        for (int pw = 1; pw < L; pw <<= 1) {
#pragma unroll
            for (int j = 0; j < 8; ++j) {
                float n00 = fmaf(m00[j], m00[j], m01[j] * m10[j]);
                float n01 = fmaf(m00[j], m01[j], m01[j] * m11[j]);
                float n10 = fmaf(m10[j], m00[j], m11[j] * m10[j]);
                float n11 = fmaf(m10[j], m01[j], m11[j] * m11[j]);
                m00[j] = n00; m01[j] = n01; m10[j] = n10; m11[j] = n11;
            }
        }
        for (int i = 0; i < c; ++i) {
            const float4* cw = (const float4*)wsBase(i);
            float4 w0 = cw[0], w1 = cw[1], w2 = cw[2], w3 = cw[3];
            float cy[8] = {w0.x, w0.z, w1.x, w1.z, w2.x, w2.z, w3.x, w3.z};
            float cz[8] = {w0.y, w0.w, w1.y, w1.w, w2.y, w2.w, w3.y, w3.w};
#pragma unroll
            for (int j = 0; j < 8; ++j) {
                float ny = fmaf(m00[j], y[j], fmaf(m01[j], z[j], cy[j]));
                float nz = fmaf(m10[j], y[j], fmaf(m11[j], z[j], cz[j]));
                y[j] = ny; z[j] = nz;
            }
        }
    }

    // full-row bases (lane covers d / e_local in staging)
    size_t bhOff = (size_t)b * Tn * TS + (size_t)h * Dn;
    const float* kb0 = K + bhOff;
    const float* qb0 = Q + bhOff;
    const float* vb0 = V + bhOff + ec * 32;
    const float* bb0 = Bt + (size_t)b * Tn * Hn + h;
    float* op = Out + bhOff + e;
    bool wlane = (dgrp == 0);

    int t0 = c * L;

    // stage one TILE of k/q/v/beta into LDS buffer `buf` via async DMA
    auto stage = [&](int buf, int tt0) {
#pragma unroll
        for (int j = 0; j < 4; ++j) {
            int s = wv * 4 + j;
            gload_lds4(kb0 + (size_t)(tt0 + s) * TS + ln, &sK[buf][s][0]);
        }
        if (WQ) {
#pragma unroll
            for (int j = 0; j < 4; ++j) {
                int s = wv * 4 + j;
                gload_lds4(qb0 + (size_t)(tt0 + s) * TS + ln, &sQ[buf][s][0]);
            }
        }
#pragma unroll
        for (int jj = 0; jj < 2; ++jj) {
            int m = wv * 2 + jj;
            int step = m * 2 + (ln >> 5);
            gload_lds4(vb0 + (size_t)(tt0 + step) * TS + (ln & 31), &sV[buf][m * 2][0]);
        }
        if (wv == 3 && ln < 16)
            gload_lds4(bb0 + (size_t)(tt0 + ln) * Hn, &sB[buf][0]);
    };

    constexpr int nT = L / TILE;
    stage(0, t0);
    __syncthreads();

    for (int ti = 0; ti < nT; ++ti) {
        int cur = ti & 1;
        if (ti + 1 < nT) stage(cur ^ 1, t0 + (ti + 1) * TILE);
        int tg = t0 + ti * TILE;
#pragma unroll 4
        for (int s = 0; s < TILE; ++s) {
            const float4* kr = (const float4*)&sK[cur][s][d0];
            float4 ka = kr[0], kb = kr[1];
            float vv = sV[cur][s][el];
            float bb = sB[cur][s];
            float bv = (DTc * bb) * vv;
            float kk[8] = {ka.x, ka.y, ka.z, ka.w, kb.x, kb.y, kb.z, kb.w};
#pragma unroll
            for (int j = 0; j < 8; ++j) {
                z[j] = fmaf(omc[j], z[j], fmaf(-aDT[j], y[j], bv * kk[j]));
                y[j] = fmaf(DTc, z[j], y[j]);
            }
            if (WQ) {
                const float4* qr = (const float4*)&sQ[cur][s][d0];
                float4 qa = qr[0], qb = qr[1];
                float qq[8] = {qa.x, qa.y, qa.z, qa.w, qb.x, qb.y, qb.z, qb.w};
                float p = 0.0f;
#pragma unroll
                for (int j = 0; j < 8; ++j) p = fmaf(qq[j], y[j], p);
                p += __shfl_xor(p, 1);
                p += __shfl_xor(p, 2);
                p += __shfl_xor(p, 4);
                if (wlane) op[(size_t)(tg + s) * TS] = p * 0.125f; // D^-0.5
            }
        }
        __syncthreads();
    }

    if (TAIL) {
        float4* cw = (float4*)wsBase(c);
#pragma unroll
        for (int j = 0; j < 4; ++j) {
            float4 w;
            w.x = y[2 * j];     w.y = z[2 * j];
            w.z = y[2 * j + 1]; w.w = z[2 * j + 1];
            cw[j] = w;
        }
    }
}

extern "C" void kernel_launch(void* const* d_in, const int* in_sizes, int n_in,
                              void* d_out, int out_size, void* d_ws, size_t ws_size,
                              hipStream_t stream) {
    const float* q  = (const float*)d_in[0];
    const float* k  = (const float*)d_in[1];
    const float* v  = (const float*)d_in[2];
    const float* bt = (const float*)d_in[3];
    const float* ow = (const float*)d_in[4];
    const float* od = (const float*)d_in[5];
    float* out = (float*)d_out;
    float* ws = (float*)d_ws;

    const size_t chunkBytes = (size_t)128 * 2 * 4096 * sizeof(float); // 4 MiB

    if (ws_size >= 3 * chunkBytes) {
        // NC=4: main 1024 blocks = exactly 4 blocks/CU resident; tail 3/4 of T.
        hipLaunchKernelGGL((linoss_k<4, true>),  dim3(768),  dim3(256), 0, stream,
                           q, k, v, bt, ow, od, out, ws);
        hipLaunchKernelGGL((linoss_k<4, false>), dim3(1024), dim3(256), 0, stream,
                           q, k, v, bt, ow, od, out, ws);
    } else if (ws_size >= chunkBytes) {
        hipLaunchKernelGGL((linoss_k<2, true>),  dim3(256),  dim3(256), 0, stream,
                           q, k, v, bt, ow, od, out, ws);
        hipLaunchKernelGGL((linoss_k<2, false>), dim3(512),  dim3(256), 0, stream,
                           q, k, v, bt, ow, od, out, ws);
    } else {
        hipLaunchKernelGGL((linoss_k<1, false>), dim3(256),  dim3(256), 0, stream,
                           q, k, v, bt, ow, od, out, ws);
    }
}